// Round 2
// baseline (402.589 us; speedup 1.0000x reference)
//
#include <hip/hip_runtime.h>
#include <hip/hip_bf16.h>
#include <cstdint>
#include <cmath>

// Problem constants (B,S,D,H) = (4, 4096, 1024, 64)
#define BB 4
#define SS 4096
#define DD 1024
#define HH 64

typedef __bf16 bf16x8 __attribute__((ext_vector_type(8)));
typedef float  f32x4  __attribute__((ext_vector_type(4)));

#define NEG_BIG (-1e30f)

__device__ __forceinline__ bf16x8 ld8(const __hip_bfloat16* p) {
    return *reinterpret_cast<const bf16x8*>(p);   // requires 16B alignment
}

// load 8 contiguous fp32 (two float4) and convert to bf16x8
__device__ __forceinline__ bf16x8 ld8f(const float* p) {
    f32x4 a = *reinterpret_cast<const f32x4*>(p);
    f32x4 b = *reinterpret_cast<const f32x4*>(p + 4);
    bf16x8 r;
    #pragma unroll
    for (int i = 0; i < 4; ++i) { r[i] = (__bf16)a[i]; r[i + 4] = (__bf16)b[i]; }
    return r;
}

__device__ __forceinline__ f32x4 mfma16(bf16x8 a, bf16x8 b, f32x4 c) {
    return __builtin_amdgcn_mfma_f32_16x16x32_bf16(a, b, c, 0, 0, 0);
}

// ---------------------------------------------------------------------------
// Projection: out[s][h] = sum_d x[s][d] * W[h][d]
// x: [16384][1024] fp32, W: [64][1024] fp32 (converted to bf16 in-flight).
// transpose_out==0: out is [16384][64] bf16 ([B,S,H] flat)
// transpose_out==1: out is [4][64][4096] bf16 (V^T, for PV B-fragments)
// ---------------------------------------------------------------------------
__global__ __launch_bounds__(256) void proj_kernel(
    const float* __restrict__ x,
    const float* __restrict__ W,
    __hip_bfloat16* __restrict__ out,
    int transpose_out)
{
    const int wave = threadIdx.x >> 6;
    const int lane = threadIdx.x & 63;
    const int l16  = lane & 15;
    const int quad = lane >> 4;
    const int row0 = blockIdx.x * 64 + wave * 16;   // 16 rows per wave

    f32x4 acc[4] = {f32x4{0,0,0,0}, f32x4{0,0,0,0}, f32x4{0,0,0,0}, f32x4{0,0,0,0}};

    const float* arow = x + (size_t)(row0 + l16) * DD + quad * 8;
    const float* wrow = W + (size_t)l16 * DD + quad * 8;
    #pragma unroll 2
    for (int k0 = 0; k0 < DD; k0 += 32) {
        bf16x8 a = ld8f(arow + k0);
        #pragma unroll
        for (int nt = 0; nt < 4; ++nt) {
            bf16x8 b = ld8f(wrow + (size_t)nt * 16 * DD + k0);
            acc[nt] = mfma16(a, b, acc[nt]);
        }
    }

    if (!transpose_out) {
        #pragma unroll
        for (int nt = 0; nt < 4; ++nt)
            #pragma unroll
            for (int j = 0; j < 4; ++j) {
                int r = row0 + quad * 4 + j;                 // C/D row = quad*4+reg
                out[(size_t)r * HH + nt * 16 + l16] = __float2bfloat16(acc[nt][j]);
            }
    } else {
        #pragma unroll
        for (int nt = 0; nt < 4; ++nt)
            #pragma unroll
            for (int j = 0; j < 4; ++j) {
                int r = row0 + quad * 4 + j;
                int b = r >> 12;           // r / 4096
                int s = r & 4095;          // r % 4096
                out[((size_t)b * HH + nt * 16 + l16) * SS + s] = __float2bfloat16(acc[nt][j]);
            }
    }
}

// ---------------------------------------------------------------------------
// Flash attention (causal), one wave per 16-query tile, KV steps of 32.
// Q,K: [B][S][64] bf16.  Vt: [B][64][S] bf16.  out: [B][S][64] fp32.
// Block = 2 waves; wave0 -> qtile blockIdx.x, wave1 -> qtile 255-blockIdx.x
// (causal load balance). Waves fully independent (wave-private LDS).
// ---------------------------------------------------------------------------
__global__ __launch_bounds__(128) void attn_kernel(
    const __hip_bfloat16* __restrict__ Q,
    const __hip_bfloat16* __restrict__ K,
    const __hip_bfloat16* __restrict__ Vt,
    float* __restrict__ out)
{
    // P transpose buffer: [16 rows][40 bf16] per wave; stride 80 B
    // -> 16B-aligned b128 reads, 2-way bank aliasing (free per m136).
    __shared__ __align__(16) __hip_bfloat16 plds[2][16][40];

    const int wave = threadIdx.x >> 6;
    const int lane = threadIdx.x & 63;
    const int l16  = lane & 15;
    const int quad = lane >> 4;
    const int b    = blockIdx.y;
    const int qt   = (wave == 0) ? (int)blockIdx.x : (255 - (int)blockIdx.x);
    const int q0   = qt * 16;

    const __hip_bfloat16* Qb = Q  + (size_t)b * SS * HH;
    const __hip_bfloat16* Kb = K  + (size_t)b * SS * HH;
    const __hip_bfloat16* Vb = Vt + (size_t)b * HH * SS;

    // Q A-fragments (K-dim = 64 -> two frags), constant over the kv loop
    bf16x8 qf0 = ld8(Qb + (size_t)(q0 + l16) * HH + quad * 8);
    bf16x8 qf1 = ld8(Qb + (size_t)(q0 + l16) * HH + 32 + quad * 8);

    f32x4 o[4] = {f32x4{0,0,0,0}, f32x4{0,0,0,0}, f32x4{0,0,0,0}, f32x4{0,0,0,0}};
    float mrow[4] = {NEG_BIG, NEG_BIG, NEG_BIG, NEG_BIG};
    float lrow[4] = {0.f, 0.f, 0.f, 0.f};

    __hip_bfloat16* pl = &plds[wave][0][0];
    const float scale = 0.125f;   // 1/sqrt(64)

    for (int kv0 = 0; kv0 < q0 + 16; kv0 += 32) {
        // ---- scores: 16 queries x 32 keys --------------------------------
        f32x4 s0 = {0, 0, 0, 0};
        f32x4 s1 = {0, 0, 0, 0};
        {
            const __hip_bfloat16* kr0 = Kb + (size_t)(kv0 + l16) * HH + quad * 8;
            const __hip_bfloat16* kr1 = kr0 + 16 * HH;
            bf16x8 k00 = ld8(kr0);        // keys kv0..+15, h 0..31
            bf16x8 k01 = ld8(kr0 + 32);   // keys kv0..+15, h 32..63
            bf16x8 k10 = ld8(kr1);
            bf16x8 k11 = ld8(kr1 + 32);
            s0 = mfma16(qf0, k00, s0);
            s0 = mfma16(qf1, k01, s0);
            s1 = mfma16(qf0, k10, s1);
            s1 = mfma16(qf1, k11, s1);
        }

        // ---- scale + causal mask ----------------------------------------
        const int key0 = kv0 + l16;
        const int key1 = kv0 + 16 + l16;
        #pragma unroll
        for (int j = 0; j < 4; ++j) {
            int qrow = q0 + quad * 4 + j;
            s0[j] = (key0 <= qrow) ? s0[j] * scale : NEG_BIG;
            s1[j] = (key1 <= qrow) ? s1[j] * scale : NEG_BIG;
        }

        // ---- row max over 32 keys (16-lane shuffle reduce) ---------------
        float mx[4];
        #pragma unroll
        for (int j = 0; j < 4; ++j) mx[j] = fmaxf(s0[j], s1[j]);
        #pragma unroll
        for (int off = 1; off < 16; off <<= 1) {
            #pragma unroll
            for (int j = 0; j < 4; ++j) mx[j] = fmaxf(mx[j], __shfl_xor(mx[j], off));
        }

        // ---- online softmax update --------------------------------------
        float alpha[4];
        #pragma unroll
        for (int j = 0; j < 4; ++j) {
            float mnew = fmaxf(mrow[j], mx[j]);     // finite: diag key in tile
            alpha[j] = __expf(mrow[j] - mnew);      // first iter: ~exp(-1e30)=0
            s0[j] = __expf(s0[j] - mnew);           // masked: ~exp(-1e30)=0
            s1[j] = __expf(s1[j] - mnew);
            mrow[j] = mnew;
        }
        float rs[4];
        #pragma unroll
        for (int j = 0; j < 4; ++j) rs[j] = s0[j] + s1[j];
        #pragma unroll
        for (int off = 1; off < 16; off <<= 1) {
            #pragma unroll
            for (int j = 0; j < 4; ++j) rs[j] += __shfl_xor(rs[j], off);
        }
        #pragma unroll
        for (int j = 0; j < 4; ++j) lrow[j] = lrow[j] * alpha[j] + rs[j];
        #pragma unroll
        for (int nt = 0; nt < 4; ++nt)
            #pragma unroll
            for (int j = 0; j < 4; ++j) o[nt][j] *= alpha[j];

        // ---- P (C/D layout) -> LDS -> A-fragment layout ------------------
        #pragma unroll
        for (int j = 0; j < 4; ++j) {
            int r = quad * 4 + j;
            pl[r * 40 + l16]      = __float2bfloat16(s0[j]);
            pl[r * 40 + 16 + l16] = __float2bfloat16(s1[j]);
        }
        asm volatile("s_waitcnt lgkmcnt(0)" ::: "memory");
        bf16x8 pf = *reinterpret_cast<const bf16x8*>(pl + l16 * 40 + quad * 8);

        // ---- O += P @ V  (B-frag from Vt: contiguous along s) ------------
        const __hip_bfloat16* vbase = Vb + (size_t)l16 * SS + kv0 + quad * 8;
        #pragma unroll
        for (int nt = 0; nt < 4; ++nt) {
            bf16x8 vf = ld8(vbase + (size_t)nt * 16 * SS);
            o[nt] = mfma16(pf, vf, o[nt]);
        }
    }

    // ---- epilogue: divide by l, store fp32 ------------------------------
    float inv[4];
    #pragma unroll
    for (int j = 0; j < 4; ++j) inv[j] = 1.0f / lrow[j];
    float* ob = out + (size_t)b * SS * HH;
    #pragma unroll
    for (int nt = 0; nt < 4; ++nt)
        #pragma unroll
        for (int j = 0; j < 4; ++j) {
            int qrow = q0 + quad * 4 + j;
            ob[(size_t)qrow * HH + nt * 16 + l16] = o[nt][j] * inv[j];
        }
}

// ---------------------------------------------------------------------------
extern "C" void kernel_launch(void* const* d_in, const int* in_sizes, int n_in,
                              void* d_out, int out_size, void* d_ws, size_t ws_size,
                              hipStream_t stream) {
    (void)in_sizes; (void)n_in; (void)out_size; (void)ws_size;
    const float* q  = (const float*)d_in[0];
    const float* k  = (const float*)d_in[1];
    const float* v  = (const float*)d_in[2];
    const float* Wq = (const float*)d_in[3];
    const float* Wk = (const float*)d_in[4];
    const float* Wv = (const float*)d_in[5];
    float* out = (float*)d_out;

    char* w = (char*)d_ws;
    __hip_bfloat16* Qw = (__hip_bfloat16*)(w);                            // 2 MB
    __hip_bfloat16* Kw = (__hip_bfloat16*)(w + (size_t)2 * 1024 * 1024);  // 2 MB
    __hip_bfloat16* Vt = (__hip_bfloat16*)(w + (size_t)4 * 1024 * 1024);  // 2 MB

    const int rows = BB * SS;                 // 16384
    proj_kernel<<<dim3(rows / 64), 256, 0, stream>>>(q, Wq, Qw, 0);
    proj_kernel<<<dim3(rows / 64), 256, 0, stream>>>(k, Wk, Kw, 0);
    proj_kernel<<<dim3(rows / 64), 256, 0, stream>>>(v, Wv, Vt, 1);

    // 256 q-tiles per batch, paired (i, 255-i) across the 2 waves of a block
    attn_kernel<<<dim3(SS / 16 / 2, BB), 128, 0, stream>>>(Qw, Kw, Vt, out);
}